// Round 1
// baseline (271.914 us; speedup 1.0000x reference)
//
#include <hip/hip_runtime.h>

// Shapes (fixed by the reference)
#define T_ 4
#define B_ 16
#define L_ 1024
#define D_ 256
#define TAU_INV 0.5f
#define V_TH 1.0f

constexpr int TB_   = T_ * B_;             // 64
constexpr int NELEM = T_ * B_ * L_ * D_;   // 16,777,216 (fits int)
constexpr int BD_   = B_ * D_;             // 4096
constexpr int TBD_  = T_ * B_ * D_;        // 16384

// ---------------- init: zero kv_sum accumulator in ws ----------------
__global__ void init_ws_kernel(float* __restrict__ kv_sum) {
    int i = blockIdx.x * blockDim.x + threadIdx.x;
    if (i < TBD_) kv_sum[i] = 0.0f;
}

// ---------------- kernel A: attn = mask?0:k*v ; partial column sums ----------------
// grid: TB_ * NCHUNK blocks, 256 threads. Each block: one (t,b), 64 rows of L.
// thread layout: d4 = (tid&63)*4 (float4 over D=256), rg = tid>>6 (4 rows in flight)
#define NCHUNK 16
#define LC 64

__global__ __launch_bounds__(256) void attn_reduce_kernel(
    const float* __restrict__ k, const float* __restrict__ v,
    const int* __restrict__ mask, float* __restrict__ attn_out,
    float* __restrict__ kv_sum)
{
    const int tid   = threadIdx.x;
    const int tb    = blockIdx.x / NCHUNK;   // 0..63  (= t*B + b)
    const int chunk = blockIdx.x % NCHUNK;   // 0..15
    const int d4    = (tid & 63) * 4;        // 0,4,...,252
    const int rg    = tid >> 6;              // 0..3

    const int base = tb * (L_ * D_);
    float4 acc = make_float4(0.f, 0.f, 0.f, 0.f);

    #pragma unroll 4
    for (int i = 0; i < LC / 4; ++i) {
        const int l   = chunk * LC + i * 4 + rg;
        const int off = base + l * D_ + d4;
        const float4 kk = *reinterpret_cast<const float4*>(k + off);
        const float4 vv = *reinterpret_cast<const float4*>(v + off);
        const int m = mask[tb * L_ + l];
        float4 a;
        if (m) {
            a = make_float4(0.f, 0.f, 0.f, 0.f);
        } else {
            a.x = kk.x * vv.x; a.y = kk.y * vv.y;
            a.z = kk.z * vv.z; a.w = kk.w * vv.w;
        }
        *reinterpret_cast<float4*>(attn_out + off) = a;
        acc.x += a.x; acc.y += a.y; acc.z += a.z; acc.w += a.w;
    }

    // reduce across the 4 row-groups (threads sharing d4)
    __shared__ float4 red[256];
    red[tid] = acc;
    __syncthreads();
    if (rg == 0) {
        float4 a0 = red[tid];
        float4 a1 = red[tid + 64];
        float4 a2 = red[tid + 128];
        float4 a3 = red[tid + 192];
        float sx = a0.x + a1.x + a2.x + a3.x;
        float sy = a0.y + a1.y + a2.y + a3.y;
        float sz = a0.z + a1.z + a2.z + a3.z;
        float sw = a0.w + a1.w + a2.w + a3.w;
        float* dst = kv_sum + tb * D_ + d4;
        atomicAdd(dst + 0, sx);
        atomicAdd(dst + 1, sy);
        atomicAdd(dst + 2, sz);
        atomicAdd(dst + 3, sw);
    }
}

// ---------------- kernel B: LIF scan over T ----------------
// one thread per (b,d); tau=2 hard-reset detach LIF
__global__ void lif_kernel(const float* __restrict__ kv_sum,
                           float* __restrict__ spikes)
{
    const int idx = blockIdx.x * blockDim.x + threadIdx.x;  // b*D + d
    if (idx >= BD_) return;
    float vm = 0.0f;
    #pragma unroll
    for (int t = 0; t < T_; ++t) {
        const float x = kv_sum[t * BD_ + idx];
        const float h = vm + (x - vm) * TAU_INV;   // charge
        const float s = (h >= V_TH) ? 1.0f : 0.0f; // fire
        spikes[t * BD_ + idx] = s;
        vm = h * (1.0f - s);                        // hard reset (detached)
    }
}

// ---------------- kernel C: output = q * spikes (broadcast over L) ----------------
__global__ __launch_bounds__(256) void qmul_kernel(
    const float* __restrict__ q, const float* __restrict__ spikes,
    float* __restrict__ out)
{
    const int i4 = blockIdx.x * blockDim.x + threadIdx.x;   // float4 index
    if (i4 >= NELEM / 4) return;
    const int d4  = (i4 & 63) * 4;   // D/4 = 64 float4 per row
    const int tbl = i4 >> 6;         // t*B*L + b*L + l
    const int tb  = tbl >> 10;       // /L  -> t*B + b
    const float4 qq = reinterpret_cast<const float4*>(q)[i4];
    const float4 ss = *reinterpret_cast<const float4*>(spikes + tb * D_ + d4);
    float4 o;
    o.x = qq.x * ss.x; o.y = qq.y * ss.y;
    o.z = qq.z * ss.z; o.w = qq.w * ss.w;
    reinterpret_cast<float4*>(out)[i4] = o;
}

extern "C" void kernel_launch(void* const* d_in, const int* in_sizes, int n_in,
                              void* d_out, int out_size, void* d_ws, size_t ws_size,
                              hipStream_t stream) {
    const float* q    = (const float*)d_in[0];
    const float* k    = (const float*)d_in[1];
    const float* v    = (const float*)d_in[2];
    const int*   mask = (const int*)d_in[3];

    float* out  = (float*)d_out;             // output: [T,B,L,D]
    float* attn = out + NELEM;               // attn:   [T,B,L,D]

    float* kv_sum = (float*)d_ws;            // [T,B,D] = 16384 floats
    float* spikes = kv_sum + TBD_;           // [T,B,D]

    // zero the accumulator (ws is poisoned each call)
    init_ws_kernel<<<(TBD_ + 255) / 256, 256, 0, stream>>>(kv_sum);

    // attn + column-sum reduction
    attn_reduce_kernel<<<TB_ * NCHUNK, 256, 0, stream>>>(k, v, mask, attn, kv_sum);

    // LIF over T
    lif_kernel<<<(BD_ + 255) / 256, 256, 0, stream>>>(kv_sum, spikes);

    // output = q * spikes
    qmul_kernel<<<NELEM / 4 / 256, 256, 0, stream>>>(q, spikes, out);
}

// Round 3
// 263.866 us; speedup vs baseline: 1.0305x; 1.0305x over previous
//
#include <hip/hip_runtime.h>

// Shapes (fixed by the reference)
#define T_ 4
#define B_ 16
#define L_ 1024
#define D_ 256
#define TAU_INV 0.5f
#define V_TH 1.0f

constexpr int TB_   = T_ * B_;             // 64
constexpr int NELEM = T_ * B_ * L_ * D_;   // 16,777,216
constexpr int BD_   = B_ * D_;             // 4096
constexpr int TBD_  = T_ * B_ * D_;        // 16384

// clang-native float4 (works with nontemporal builtins)
typedef float f4 __attribute__((ext_vector_type(4)));

// K1 tiling: each block = one (t,b) x one chunk of LC rows
#define NCHUNK 32
#define LC 32   // L_ / NCHUNK

// ---------------- K1: attn = mask?0:k*v ; per-chunk partial column sums ----------------
// grid: TB_*NCHUNK = 2048 blocks, 256 threads (8 blocks/CU -> 32 waves/CU)
// lanes: d4 = (tid&63)*4 covers D=256 as float4; rg = tid>>6 -> 4 rows in flight
__global__ __launch_bounds__(256) void attn_partial_kernel(
    const float* __restrict__ k, const float* __restrict__ v,
    const int* __restrict__ mask, float* __restrict__ attn_out,
    float* __restrict__ partials)
{
    const int tid   = threadIdx.x;
    const int tb    = blockIdx.x / NCHUNK;   // 0..63  (= t*B + b)
    const int chunk = blockIdx.x % NCHUNK;   // 0..31
    const int d4    = (tid & 63) * 4;
    const int rg    = tid >> 6;              // 0..3

    const int base = tb * (L_ * D_);
    f4 acc = (f4)(0.0f);

    #pragma unroll
    for (int i = 0; i < LC / 4; ++i) {
        const int l   = chunk * LC + i * 4 + rg;
        const int off = base + l * D_ + d4;
        const f4 kk = __builtin_nontemporal_load(reinterpret_cast<const f4*>(k + off));
        const f4 vv = __builtin_nontemporal_load(reinterpret_cast<const f4*>(v + off));
        const int m = mask[tb * L_ + l];
        f4 a = m ? (f4)(0.0f) : (kk * vv);
        __builtin_nontemporal_store(a, reinterpret_cast<f4*>(attn_out + off));
        acc += a;
    }

    // reduce across the 4 row-groups (threads sharing d4), then plain store
    __shared__ f4 red[256];
    red[tid] = acc;
    __syncthreads();
    if (rg == 0) {
        f4 s = red[tid] + red[tid + 64] + red[tid + 128] + red[tid + 192];
        // partials[(tb*NCHUNK + chunk)*D + d4]
        *reinterpret_cast<f4*>(partials + (tb * NCHUNK + chunk) * D_ + d4) = s;
    }
}

// ---------------- K2: sum partials + LIF scan over T ----------------
// one thread per (b,d); 16 blocks x 256
__global__ void lif_kernel(const float* __restrict__ partials,
                           float* __restrict__ spikes)
{
    const int idx = blockIdx.x * blockDim.x + threadIdx.x;  // b*D + d
    if (idx >= BD_) return;
    const int b = idx >> 8;      // /D
    const int d = idx & 255;

    float vm = 0.0f;
    #pragma unroll
    for (int t = 0; t < T_; ++t) {
        const int tb = t * B_ + b;
        float x = 0.0f;
        #pragma unroll
        for (int c = 0; c < NCHUNK; ++c) {
            x += partials[(tb * NCHUNK + c) * D_ + d];   // coalesced across lanes
        }
        const float h = vm + (x - vm) * TAU_INV;   // charge
        const float s = (h >= V_TH) ? 1.0f : 0.0f; // fire
        spikes[t * BD_ + idx] = s;
        vm = h * (1.0f - s);                        // detached hard reset
    }
}

// ---------------- K3: output = q * spikes (broadcast over L) ----------------
__global__ __launch_bounds__(256) void qmul_kernel(
    const float* __restrict__ q, const float* __restrict__ spikes,
    float* __restrict__ out)
{
    const int i4 = blockIdx.x * blockDim.x + threadIdx.x;   // float4 index
    if (i4 >= NELEM / 4) return;
    const int d4  = (i4 & 63) * 4;   // 64 float4 per row
    const int tbl = i4 >> 6;         // t*B*L + b*L + l
    const int tb  = tbl >> 10;       // -> t*B + b
    const f4 qq = __builtin_nontemporal_load(reinterpret_cast<const f4*>(q) + i4);
    const f4 ss = *reinterpret_cast<const f4*>(spikes + tb * D_ + d4);
    const f4 o  = qq * ss;
    __builtin_nontemporal_store(o, reinterpret_cast<f4*>(out) + i4);
}

extern "C" void kernel_launch(void* const* d_in, const int* in_sizes, int n_in,
                              void* d_out, int out_size, void* d_ws, size_t ws_size,
                              hipStream_t stream) {
    const float* q    = (const float*)d_in[0];
    const float* k    = (const float*)d_in[1];
    const float* v    = (const float*)d_in[2];
    const int*   mask = (const int*)d_in[3];

    float* out  = (float*)d_out;             // output: [T,B,L,D]
    float* attn = out + NELEM;               // attn:   [T,B,L,D]

    float* partials = (float*)d_ws;          // [TB, NCHUNK, D] = 512K floats (2 MB)
    float* spikes   = partials + TB_ * NCHUNK * D_;  // [T,B,D]

    attn_partial_kernel<<<TB_ * NCHUNK, 256, 0, stream>>>(k, v, mask, attn, partials);
    lif_kernel<<<(BD_ + 255) / 256, 256, 0, stream>>>(partials, spikes);
    qmul_kernel<<<NELEM / 4 / 256, 256, 0, stream>>>(q, spikes, out);
}

// Round 5
// 258.454 us; speedup vs baseline: 1.0521x; 1.0209x over previous
//
#include <hip/hip_runtime.h>

// Shapes (fixed by the reference)
#define T_ 4
#define B_ 16
#define L_ 1024
#define D_ 256
#define TAU_INV 0.5f
#define V_TH 1.0f

constexpr int TB_   = T_ * B_;             // 64
constexpr int NELEM = T_ * B_ * L_ * D_;   // 16,777,216

// clang-native float4 (works with nontemporal builtins)
typedef float f4 __attribute__((ext_vector_type(4)));

#define NCHUNK 32
#define LC 32   // L_ / NCHUNK

// ---------------- K1: attn = mask?0:k*v ; per-chunk partial column sums ----------------
// grid: TB_*NCHUNK = 2048 blocks, 256 threads.
// One wave = one row (rg = tid>>6 uniform per wave) -> masked-row branch is
// wave-uniform and skips the k/v loads entirely (~50% of rows).
__global__ __launch_bounds__(256) void attn_partial_kernel(
    const float* __restrict__ k, const float* __restrict__ v,
    const int* __restrict__ mask, float* __restrict__ attn_out,
    float* __restrict__ partials)
{
    const int tid   = threadIdx.x;
    const int tb    = blockIdx.x >> 5;       // / NCHUNK
    const int chunk = blockIdx.x & 31;       // % NCHUNK
    const int lane  = tid & 63;
    const int d4    = lane * 4;
    const int rg    = tid >> 6;              // 0..3

    const int base = tb * (L_ * D_);
    f4 acc = (f4)(0.0f);

    #pragma unroll
    for (int i = 0; i < LC / 4; ++i) {
        const int l   = chunk * LC + i * 4 + rg;
        const int off = base + l * D_ + d4;
        const int m   = mask[tb * L_ + l];   // wave-uniform
        f4 a;
        if (m) {
            a = (f4)(0.0f);
        } else {
            const f4 kk = __builtin_nontemporal_load(reinterpret_cast<const f4*>(k + off));
            const f4 vv = __builtin_nontemporal_load(reinterpret_cast<const f4*>(v + off));
            a = kk * vv;
            acc += a;
        }
        __builtin_nontemporal_store(a, reinterpret_cast<f4*>(attn_out + off));
    }

    // reduce across the 4 row-groups (threads sharing d4)
    __shared__ f4 red[256];
    red[tid] = acc;
    __syncthreads();
    if (rg == 0) {
        f4 s = red[tid] + red[tid + 64] + red[tid + 128] + red[tid + 192];
        *reinterpret_cast<f4*>(partials + (tb * NCHUNK + chunk) * D_ + d4) = s;
    }
}

// ---------------- K2': fused {partials -> LIF -> spikes} + output = q*spike ----------------
// grid: TB_ * 16 = 1024 blocks, 256 threads. block = (t, b, 64-row chunk).
// Each block re-derives the spike vector for its (t,b) from the 2 MB partials
// (L2-resident; 16x redundancy = ~134 MB of L2 reads ~= 4 us aggregate), then
// streams its 64 q-rows -> out.
__global__ __launch_bounds__(256) void lif_qmul_kernel(
    const float* __restrict__ q, const float* __restrict__ partials,
    float* __restrict__ out)
{
    const int tid  = threadIdx.x;
    const int tb   = blockIdx.x >> 4;        // 0..63  (= t*B + b)
    const int c16  = blockIdx.x & 15;        // 0..15  (64-row chunk)
    const int t    = tb >> 4;                // / B_
    const int b    = tb & 15;
    const int lane = tid & 63;
    const int d4   = lane * 4;
    const int rg   = tid >> 6;

    // Step A: per-thread partial sums over 8 chunks, for every t'
    f4 s[T_];
    #pragma unroll
    for (int tt = 0; tt < T_; ++tt) {
        f4 a = (f4)(0.0f);
        #pragma unroll
        for (int j = 0; j < 8; ++j) {
            const int cc = rg * 8 + j;
            a += *reinterpret_cast<const f4*>(partials + ((tt * B_ + b) * NCHUNK + cc) * D_ + d4);
        }
        s[tt] = a;
    }

    // Step B: LDS reduce over rg, then per-thread LIF over T
    __shared__ f4 red[4][T_][64];
    #pragma unroll
    for (int tt = 0; tt < T_; ++tt) red[rg][tt][lane] = s[tt];
    __syncthreads();

    f4 spike = (f4)(0.0f);
    {
        f4 vm = (f4)(0.0f);
        #pragma unroll
        for (int tt = 0; tt < T_; ++tt) {
            const f4 x = red[0][tt][lane] + red[1][tt][lane]
                       + red[2][tt][lane] + red[3][tt][lane];
            const f4 h = vm + (x - vm) * TAU_INV;    // charge
            f4 sp;
            sp.x = (h.x >= V_TH) ? 1.0f : 0.0f;
            sp.y = (h.y >= V_TH) ? 1.0f : 0.0f;
            sp.z = (h.z >= V_TH) ? 1.0f : 0.0f;
            sp.w = (h.w >= V_TH) ? 1.0f : 0.0f;
            if (tt == t) spike = sp;
            vm = h * ((f4)(1.0f) - sp);              // detached hard reset
        }
    }

    // Step C: stream 64 rows of q -> out
    const int base = tb * (L_ * D_);
    #pragma unroll
    for (int i = 0; i < 16; ++i) {
        const int l   = c16 * 64 + i * 4 + rg;
        const int off = base + l * D_ + d4;
        const f4 qq = __builtin_nontemporal_load(reinterpret_cast<const f4*>(q + off));
        __builtin_nontemporal_store(qq * spike, reinterpret_cast<f4*>(out + off));
    }
}

extern "C" void kernel_launch(void* const* d_in, const int* in_sizes, int n_in,
                              void* d_out, int out_size, void* d_ws, size_t ws_size,
                              hipStream_t stream) {
    const float* q    = (const float*)d_in[0];
    const float* k    = (const float*)d_in[1];
    const float* v    = (const float*)d_in[2];
    const int*   mask = (const int*)d_in[3];

    float* out  = (float*)d_out;             // output: [T,B,L,D]
    float* attn = out + NELEM;               // attn:   [T,B,L,D]

    float* partials = (float*)d_ws;          // [TB, NCHUNK, D] = 512K floats (2 MB)

    attn_partial_kernel<<<TB_ * NCHUNK, 256, 0, stream>>>(k, v, mask, attn, partials);
    lif_qmul_kernel<<<TB_ * 16, 256, 0, stream>>>(q, partials, out);
}